// Round 3
// baseline (135.051 us; speedup 1.0000x reference)
//
#include <hip/hip_runtime.h>
#include <math.h>

// N=M=8192, d=64, P=64, N_FT=1024 -> folded k = 1..512, active band contiguous
#define N_SRC 8192
#define D_DIM 64
#define P_SL  64
#define KH    512

// ws float offsets
#define WS_NM    0                       // norm_max (float bits, atomicMax as uint)
#define WS_KMINE 1                       // uint: max(513 - k) over active k
#define WS_KMAXE 2                       // uint: max k over active k
#define WS_WL    16                      // dense folded weights, index k-1 [512]
#define WS_CS    (16 + KH)               // wk*C, wk*S per (p, kidx): P*KH*2
#define WS_A     (WS_CS + P_SL*KH*2)     // projections of x: P*N
#define WS_B     (WS_A + P_SL*N_SRC)     // projections of y: P*N

__device__ __forceinline__ void sincos2pi(float t, float& s, float& c) {
    // v_sin_f32 / v_cos_f32 take REVOLUTIONS; fract maps into valid range.
    float f = __builtin_amdgcn_fractf(t);
    s = __builtin_amdgcn_sinf(f);
    c = __builtin_amdgcn_cosf(f);
}

// K1: norm_max over all 16384 rows
__global__ __launch_bounds__(256) void k_normmax(const float* __restrict__ x,
                                                 const float* __restrict__ y,
                                                 float* __restrict__ ws) {
    int r = blockIdx.x * 256 + threadIdx.x;
    const float* row = (r < N_SRC) ? (x + (size_t)r * D_DIM)
                                   : (y + (size_t)(r - N_SRC) * D_DIM);
    const float4* r4 = (const float4*)row;
    float ss = 0.f;
#pragma unroll
    for (int j = 0; j < D_DIM / 4; ++j) {
        float4 v = r4[j];
        ss = fmaf(v.x, v.x, ss); ss = fmaf(v.y, v.y, ss);
        ss = fmaf(v.z, v.z, ss); ss = fmaf(v.w, v.w, ss);
    }
    float nm = sqrtf(ss);
    for (int o = 32; o; o >>= 1) nm = fmaxf(nm, __shfl_xor(nm, o, 64));
    if ((threadIdx.x & 63) == 0)
        atomicMax((unsigned int*)(ws + WS_NM), __float_as_uint(nm));
}

// K2: dense folded kft weights (f32 log-space, matches reference) + band bounds.
__global__ void k_kft(const float* __restrict__ scale, float* __restrict__ ws) {
    int k = threadIdx.x + 1;  // 1..512
    float nm = ws[WS_NM];
    float sf = 0.3f / nm;
    float sr = scale[0] * sf;
    float s2 = sr * sr;
    float a = 19.7392088f * s2;  // 2*pi^2*sigma^2
    float logv = 32.0f * logf(a) + 63.0f * logf((float)k)
               - a * (float)k * (float)k - 78.0922235f;  // lgamma(32)
    float v = expf(logv);
    float wk = ((k == KH) ? 1.0f : 2.0f) * v * (1.0f / (float)P_SL);
    ws[WS_WL + k - 1] = wk;
    if (v > 1e-18f) {
        atomicMax((unsigned int*)ws + WS_KMINE, (unsigned int)(513 - k));
        atomicMax((unsigned int*)ws + WS_KMAXE, (unsigned int)k);
    }
}

// K3: A[p][n] = sf*(x_n . xi_p). Row kept in registers; xi reads wave-uniform.
// grid.x MUST be N_SRC/128 = 64 (Round-2 crash was 128 here -> OOB).
__global__ __launch_bounds__(128) void k_proj(const float* __restrict__ x,
                                              const float* __restrict__ y,
                                              const float* __restrict__ xis,
                                              float* __restrict__ ws) {
    int row   = blockIdx.x * 128 + threadIdx.x;   // 0..8191
    int which = blockIdx.z;
    int p0    = blockIdx.y * 32;
    const float* src = which ? y : x;
    float* dst = ws + (which ? WS_B : WS_A);
    float sf = 0.3f / ws[WS_NM];
    float4 r[16];
    const float4* rp = (const float4*)(src + (size_t)row * D_DIM);
#pragma unroll
    for (int j = 0; j < 16; ++j) r[j] = rp[j];
    for (int pi = 0; pi < 32; ++pi) {
        int p = p0 + pi;
        const float4* xi = (const float4*)(xis + p * D_DIM);
        float acc = 0.f;
#pragma unroll
        for (int j = 0; j < 16; ++j) {
            float4 u = xi[j];
            acc = fmaf(r[j].x, u.x, acc); acc = fmaf(r[j].y, u.y, acc);
            acc = fmaf(r[j].z, u.z, acc); acc = fmaf(r[j].w, u.w, acc);
        }
        dst[p * N_SRC + row] = sf * acc;
    }
}

// K4: adjoint NDFT. lane = frequency index, scalar loop over source points
// (point data wave-uniform per iteration). No LDS in hot loop.
__global__ __launch_bounds__(256) void k_adjoint(const float* __restrict__ xw,
                                                 const float* __restrict__ wsA,
                                                 const float* __restrict__ wsWL,
                                                 const unsigned int* __restrict__ hdr,
                                                 float* __restrict__ wsCS) {
    __shared__ float accC[64], accS[64];
    int p = blockIdx.y, chunk = blockIdx.x;
    int tid = threadIdx.x, lane = tid & 63;
    int wv = __builtin_amdgcn_readfirstlane(tid >> 6);  // provably wave-uniform
    int kmin = 513 - (int)hdr[WS_KMINE];
    int kmax = (int)hdr[WS_KMAXE];
    int kcnt = kmax - kmin + 1;  // ~60-110 for this problem; loop handles any value
    int base = chunk * 1024 + wv * 256;
    const float* ap = wsA + p * N_SRC + base;
    const float* wp = xw + base;
    for (int kbase = 0; kbase < kcnt; kbase += 64) {
        __syncthreads();
        if (tid < 64) { accC[tid] = 0.f; accS[tid] = 0.f; }
        __syncthreads();
        int kidx = kbase + lane;
        float fk = (float)(kmin + kidx);
        float ca = 0.f, sa = 0.f;
        for (int j = 0; j < 256; ++j) {
            float aj = ap[j];   // wave-uniform address -> scalar/broadcast load
            float wj = wp[j];
            float t = fk * aj;
            float s, c; sincos2pi(t, s, c);
            ca = fmaf(wj, c, ca);
            sa = fmaf(wj, s, sa);
        }
        atomicAdd(&accC[lane], ca);
        atomicAdd(&accS[lane], sa);
        __syncthreads();
        if (tid < 64 && kbase + tid < kcnt) {
            int kk = kmin + kbase + tid;
            float wk = wsWL[kk - 1];
            atomicAdd(wsCS + ((size_t)p * KH + kbase + tid) * 2 + 0, wk * accC[tid]);
            atomicAdd(wsCS + ((size_t)p * KH + kbase + tid) * 2 + 1, wk * accS[tid]);
        }
    }
}

// K5: forward NDFT via complex recurrence over consecutive k. No LDS, no
// per-k transcendentals: 6 VALU ops per frequency.
__global__ __launch_bounds__(256) void k_forward(const float* __restrict__ wsB,
                                                 const float* __restrict__ wsCS,
                                                 const unsigned int* __restrict__ hdr,
                                                 float* __restrict__ out) {
    int p = blockIdx.y;
    int m = blockIdx.x * 256 + threadIdx.x;
    int kmin = 513 - (int)hdr[WS_KMINE];
    int kmax = (int)hdr[WS_KMAXE];
    int kcnt = kmax - kmin + 1;
    float b = wsB[p * N_SRC + m];
    float s1, c1; sincos2pi(b, s1, c1);                 // step rotation e^{2*pi*i*b}
    float s, c;  sincos2pi(b * (float)kmin, s, c);      // start at k = kmin
    const float2* cs = (const float2*)wsCS + (size_t)p * KH;
    float sum = 0.f;
    for (int kidx = 0; kidx < kcnt; ++kidx) {
        float2 q = cs[kidx];      // wave-uniform -> scalar/broadcast load
        sum = fmaf(q.x, c, sum);
        sum = fmaf(q.y, s, sum);
        float t  = s * s1;
        float cn = fmaf(c, c1, -t);
        s  = fmaf(s, c1, c * s1);
        c  = cn;
    }
    atomicAdd(out + m, sum);
}

extern "C" void kernel_launch(void* const* d_in, const int* in_sizes, int n_in,
                              void* d_out, int out_size, void* d_ws, size_t ws_size,
                              hipStream_t stream) {
    const float* x     = (const float*)d_in[0];
    const float* y     = (const float*)d_in[1];
    const float* xw    = (const float*)d_in[2];
    const float* scale = (const float*)d_in[3];
    const float* xis   = (const float*)d_in[4];
    float* ws  = (float*)d_ws;
    float* out = (float*)d_out;

    // one memset covers header + weights + C/S accumulators
    hipMemsetAsync(ws, 0, (size_t)(WS_CS + P_SL * KH * 2) * sizeof(float), stream);
    hipMemsetAsync(out, 0, (size_t)N_SRC * sizeof(float), stream);

    k_normmax<<<dim3(64),        dim3(256), 0, stream>>>(x, y, ws);
    k_kft    <<<dim3(1),         dim3(512), 0, stream>>>(scale, ws);
    k_proj   <<<dim3(64, 2, 2),  dim3(128), 0, stream>>>(x, y, xis, ws);
    k_adjoint<<<dim3(8, 64),     dim3(256), 0, stream>>>(
        xw, ws + WS_A, ws + WS_WL, (const unsigned int*)ws, ws + WS_CS);
    k_forward<<<dim3(32, 64),    dim3(256), 0, stream>>>(
        ws + WS_B, ws + WS_CS, (const unsigned int*)ws, out);
}